// Round 2
// baseline (789.152 us; speedup 1.0000x reference)
//
#include <hip/hip_runtime.h>
#include <hip/hip_bf16.h>
#include <cstdint>
#include <cstddef>

// ============================================================================
// ResMLP fused kernel for MI355X (gfx950)
//
// Design (round 2 — round 1 + trivially-copyable bf16 packing):
//  - Prep kernel: transpose all weights to bf16 [n][k] layouts in d_ws:
//      wt  [32][160][160]  (layer weights, W^T)
//      ewt [160][800]      (embed W^T, k zero-padded 784->800)
//      hwt [16][160]       (head W^T, n zero-padded 10->16)
//  - Main kernel: 1024 blocks x 256 threads, each block owns 64 rows through
//    the WHOLE network (embed -> 32 residual layers -> head).
//    4 waves = 2(M) x 2(N); wave tile = 32 rows x 80 cols.
//    Residual stream kept in fp32 registers (C-layout). H (bf16, A-layout,
//    stride 168) in LDS; W streamed through a 2-slot ring of 32-k chunks
//    (slot stride 40) with register prefetch overlapping MFMA.
//    MFMA: v_mfma_f32_16x16x32_bf16.
// ============================================================================

typedef __attribute__((ext_vector_type(8))) short bfrag8;   // 8 x bf16 (4 VGPR)
typedef __attribute__((ext_vector_type(4))) float facc4;    // 4 x f32 acc

#define MFMA16(a, b, c) __builtin_amdgcn_mfma_f32_16x16x32_bf16((a), (b), (c), 0, 0, 0)

// Round-to-nearest-even f32 -> bf16 on raw bits (no HIP class types, which
// are not trivially copyable in this ROCm and break __builtin_bit_cast).
static __device__ __forceinline__ uint16_t f2bf16u(float v) {
    uint32_t u = __builtin_bit_cast(uint32_t, v);
    uint32_t r = u + 0x7FFFu + ((u >> 16) & 1u);
    return (uint16_t)(r >> 16);
}
static __device__ __forceinline__ uint32_t pack2_bf16(float lo, float hi) {
    return (uint32_t)f2bf16u(lo) | ((uint32_t)f2bf16u(hi) << 16);
}

// ---------------------------------------------------------------------------
// Prep: transpose + cast weights. Grid = 926 blocks x 256 threads.
//   blocks [0,800):   layer_w  [l][160k][160n] -> wt[l][n][k]
//   blocks [800,925): embed_w  [784k][160n]    -> ewt[n][k], k padded to 800
//   block  925:       head_w   [160k][10n]     -> hwt[n][k], n padded to 16
// ---------------------------------------------------------------------------
__global__ __launch_bounds__(256) void resmlp_prep(
    const float* __restrict__ embed_w, const float* __restrict__ layer_w,
    const float* __restrict__ head_w,
    uint16_t* __restrict__ wt, uint16_t* __restrict__ ewt, uint16_t* __restrict__ hwt)
{
    int b = blockIdx.x;
    if (b == 925) {
        for (int i = threadIdx.x; i < 16 * 160; i += 256) {
            int n = i / 160, k = i % 160;
            float v = (n < 10) ? head_w[k * 10 + n] : 0.f;
            hwt[n * 160 + k] = f2bf16u(v);
        }
        return;
    }
    __shared__ float tile[32][33];
    const float* src; uint16_t* dst; int R, dstStride, rt, ct;
    if (b < 800) {
        int l = b / 25, t = b % 25; rt = t / 5; ct = t % 5;
        src = layer_w + (size_t)l * 25600; dst = wt + (size_t)l * 25600;
        R = 160; dstStride = 160;
    } else {
        int t = b - 800; rt = t / 5; ct = t % 5;
        src = embed_w; dst = ewt; R = 784; dstStride = 800;
    }
    int tx = threadIdx.x & 31, ty = threadIdx.x >> 5;
#pragma unroll
    for (int j = 0; j < 4; ++j) {
        int r = rt * 32 + ty + j * 8, c = ct * 32 + tx;     // r = k index, c = n index
        tile[ty + j * 8][tx] = (r < R) ? src[(size_t)r * 160 + c] : 0.f;
    }
    __syncthreads();
#pragma unroll
    for (int j = 0; j < 4; ++j) {
        int drow = ct * 32 + ty + j * 8;   // n
        int dcol = rt * 32 + tx;           // k (padded range ok)
        dst[(size_t)drow * dstStride + dcol] = f2bf16u(tile[tx][ty + j * 8]);
    }
}

// ---------------------------------------------------------------------------
// Main fused kernel.
// LDS map (uint16 elements):
//   Hs   [64][168]   @ 0        (10752)  bf16 A-layout tile / embed x-chunks
//   slot0 [160][40]  @ 10752    (6400)   W^T k-chunk ring slot 0 (32k + 8 pad)
//   slot1 [160][40]  @ 17152    (6400)   ring slot 1
// Chunk stream c = 0..189: 25 embed (ewt), 160 layers (wt), 5 head (hwt).
// akk = c % 5 selects the 32-k slice of the current 160-k A panel.
// ---------------------------------------------------------------------------

__device__ __forceinline__ void stage_x_group(const float* __restrict__ x,
                                              uint16_t* Hs, int r0, int tid, int g)
{
    const int row = tid >> 2;          // 0..63
    const int kc  = g * 160;
    const float* xr = x + (size_t)(r0 + row) * 784 + kc;
#pragma unroll
    for (int j = 0; j < 10; ++j) {
        int c4 = (tid & 3) + j * 4;    // 0..39 (float4 index inside 160-k chunk)
        float4 v;
        if (kc + c4 * 4 < 784) v = *(const float4*)(xr + c4 * 4);
        else                   v = make_float4(0.f, 0.f, 0.f, 0.f);
        uint2 u;
        u.x = pack2_bf16(v.x, v.y);
        u.y = pack2_bf16(v.z, v.w);
        *(uint2*)((char*)Hs + row * 336 + c4 * 8) = u;
    }
}

__device__ __forceinline__ void writeback_h(uint16_t* Hs, const facc4 (&resid)[2][5],
                                            int mg, int NB, int q, int ln)
{
#pragma unroll
    for (int mt = 0; mt < 2; ++mt) {
#pragma unroll
        for (int nt = 0; nt < 5; ++nt) {
#pragma unroll
            for (int r = 0; r < 4; ++r) {
                float v = resid[mt][nt][r];
                // neighbor (lane^1) value via DPP quad_perm [1,0,3,2] (VALU pipe, not DS)
                float nb = __builtin_bit_cast(float,
                    __builtin_amdgcn_mov_dpp(__builtin_bit_cast(int, v), 0xB1, 0xF, 0xF, true));
                uint32_t pk = (ln & 1) ? pack2_bf16(nb, v) : pack2_bf16(v, nb);
                if (((ln ^ r) & 1) == 0) {      // even lanes write even r, odd write odd r
                    int row = mg * 32 + mt * 16 + q * 4 + r;
                    int col = NB + nt * 16 + (ln & ~1);
                    *(uint32_t*)((char*)Hs + row * 336 + col * 2) = pk;
                }
            }
        }
    }
}

__global__ __launch_bounds__(256, 2) void resmlp_main(
    const float* __restrict__ x,
    const float* __restrict__ embed_b,
    const float* __restrict__ head_b,
    const uint16_t* __restrict__ wt,
    const uint16_t* __restrict__ ewt,
    const uint16_t* __restrict__ hwt,
    float* __restrict__ out)
{
    __shared__ __align__(16) uint16_t lds[23552];
    uint16_t* Hs    = lds;
    uint16_t* slotA = lds + 10752;
    uint16_t* slotB = lds + 17152;

    const int tid  = threadIdx.x;
    const int lane = tid & 63;
    const int wave = tid >> 6;
    const int mg = wave >> 1;          // 0..1  (32-row group)
    const int ng = wave & 1;           // 0..1  (80-col group)
    const int q  = lane >> 4;          // 0..3
    const int ln = lane & 15;          // 0..15
    const int NB = ng * 80;
    const int r0 = blockIdx.x * 64;

    float bias[5];
#pragma unroll
    for (int nt = 0; nt < 5; ++nt) bias[nt] = embed_b[NB + nt * 16 + ln];
    const float hb = (ln < 10) ? head_b[ln] : 0.f;

    facc4 acc[2][5];
    facc4 resid[2][5];
#pragma unroll
    for (int mt = 0; mt < 2; ++mt)
#pragma unroll
        for (int nt = 0; nt < 5; ++nt) acc[mt][nt] = (facc4){0.f, 0.f, 0.f, 0.f};

    // ---- prologue: stage x group 0 and W chunk 0 (ewt k=0..31) into slot0 ----
    stage_x_group(x, Hs, r0, tid, 0);
#pragma unroll
    for (int j = 0; j < 3; ++j) {
        int i = tid + j * 256;
        if (i < 640) {
            int n = i >> 2, u = i & 3;
            uint4 v = *(const uint4*)((const char*)ewt + n * 1600 + u * 16);
            *(uint4*)((char*)slotA + n * 80 + u * 16) = v;
        }
    }
    __syncthreads();

    const int abase = (mg * 32 + ln) * 168 + q * 8;   // element offset in Hs

    for (int c = 0; c < 190; ++c) {
        const int akk = c % 5;

        // ---- prefetch W chunk c+1 into registers (global, overlaps MFMA) ----
        uint4 pf0, pf1, pf2;
        const uint8_t* pbase = nullptr; int pstride = 0, prows = 0;
        if (c < 189) {
            int d = c + 1;
            if (d < 25) {
                pbase = (const uint8_t*)ewt + d * 64; pstride = 1600; prows = 160;
            } else if (d < 185) {
                int cl = d - 25;
                pbase = (const uint8_t*)wt + (size_t)(cl / 5) * 51200 + (cl % 5) * 64;
                pstride = 320; prows = 160;
            } else {
                pbase = (const uint8_t*)hwt + (d - 185) * 64; pstride = 320; prows = 16;
            }
            {   int i = tid;       int n = i >> 2, u = i & 3;
                if (n < prows) pf0 = *(const uint4*)(pbase + n * pstride + u * 16); }
            {   int i = tid + 256; int n = i >> 2, u = i & 3;
                if (n < prows) pf1 = *(const uint4*)(pbase + n * pstride + u * 16); }
            {   int i = tid + 512; int n = i >> 2, u = i & 3;
                if (i < 640 && n < prows) pf2 = *(const uint4*)(pbase + n * pstride + u * 16); }
        }

        // ---- compute chunk c ----
        const uint16_t* S = (c & 1) ? slotB : slotA;
        if (c < 185) {
            bfrag8 a0 = *(const bfrag8*)(Hs + abase + akk * 32);
            bfrag8 a1 = *(const bfrag8*)(Hs + abase + 16 * 168 + akk * 32);
#pragma unroll
            for (int nt = 0; nt < 5; ++nt) {
                bfrag8 b = *(const bfrag8*)(S + (NB + nt * 16 + ln) * 40 + q * 8);
                acc[0][nt] = MFMA16(a0, b, acc[0][nt]);
                acc[1][nt] = MFMA16(a1, b, acc[1][nt]);
            }
        } else if (ng == 0) {   // head: only n-tile 0 is meaningful
            bfrag8 a0 = *(const bfrag8*)(Hs + abase + akk * 32);
            bfrag8 a1 = *(const bfrag8*)(Hs + abase + 16 * 168 + akk * 32);
            bfrag8 b  = *(const bfrag8*)(S + ln * 40 + q * 8);
            acc[0][0] = MFMA16(a0, b, acc[0][0]);
            acc[1][0] = MFMA16(a1, b, acc[1][0]);
        }

        // ---- commit prefetched W chunk c+1 to the other slot ----
        if (c < 189) {
            uint16_t* D = ((c + 1) & 1) ? slotB : slotA;
            {   int i = tid;       int n = i >> 2, u = i & 3;
                if (n < prows) *(uint4*)((char*)D + n * 80 + u * 16) = pf0; }
            {   int i = tid + 256; int n = i >> 2, u = i & 3;
                if (n < prows) *(uint4*)((char*)D + n * 80 + u * 16) = pf1; }
            {   int i = tid + 512; int n = i >> 2, u = i & 3;
                if (i < 640 && n < prows) *(uint4*)((char*)D + n * 80 + u * 16) = pf2; }
        }
        __syncthreads();

        // ---- boundary work every 5 chunks (end of a 160-k panel) ----
        if (akk == 4) {
            if (c < 24) {
                // mid-embed: stage next x group
                stage_x_group(x, Hs, r0, tid, (c + 1) / 5);
            } else if (c == 24) {
                // end of embed: resid = acc + bias; write H; zero acc
#pragma unroll
                for (int mt = 0; mt < 2; ++mt)
#pragma unroll
                    for (int nt = 0; nt < 5; ++nt) {
#pragma unroll
                        for (int r = 0; r < 4; ++r)
                            resid[mt][nt][r] = acc[mt][nt][r] + bias[nt];
                        acc[mt][nt] = (facc4){0.f, 0.f, 0.f, 0.f};
                    }
                writeback_h(Hs, resid, mg, NB, q, ln);
            } else if (c < 185) {
                // end of layer: resid += relu(acc); write H; zero acc
#pragma unroll
                for (int mt = 0; mt < 2; ++mt)
#pragma unroll
                    for (int nt = 0; nt < 5; ++nt) {
#pragma unroll
                        for (int r = 0; r < 4; ++r)
                            resid[mt][nt][r] += fmaxf(acc[mt][nt][r], 0.f);
                        acc[mt][nt] = (facc4){0.f, 0.f, 0.f, 0.f};
                    }
                writeback_h(Hs, resid, mg, NB, q, ln);
            } else {
                // c == 189: head epilogue + store
                if (ng == 0) {
#pragma unroll
                    for (int mt = 0; mt < 2; ++mt)
#pragma unroll
                        for (int r = 0; r < 4; ++r) {
                            int row = r0 + mg * 32 + mt * 16 + q * 4 + r;
                            if (ln < 10) out[row * 10 + ln] = acc[mt][0][r] + hb;
                        }
                }
            }
            __syncthreads();
        }
    }
}

// ---------------------------------------------------------------------------
extern "C" void kernel_launch(void* const* d_in, const int* in_sizes, int n_in,
                              void* d_out, int out_size, void* d_ws, size_t ws_size,
                              hipStream_t stream) {
    (void)in_sizes; (void)n_in; (void)out_size; (void)ws_size;
    const float* x       = (const float*)d_in[0];
    const float* embed_w = (const float*)d_in[1];
    const float* embed_b = (const float*)d_in[2];
    const float* layer_w = (const float*)d_in[3];
    const float* head_w  = (const float*)d_in[4];
    const float* head_b  = (const float*)d_in[5];
    float* out = (float*)d_out;

    uint16_t* wt  = (uint16_t*)d_ws;          // 32*160*160 = 819200 elems
    uint16_t* ewt = wt + 819200;              // 160*800    = 128000 elems
    uint16_t* hwt = ewt + 128000;             // 16*160     = 2560 elems

    resmlp_prep<<<926, 256, 0, stream>>>(embed_w, layer_w, head_w, wt, ewt, hwt);
    resmlp_main<<<1024, 256, 0, stream>>>(x, embed_b, head_b, wt, ewt, hwt, out);
}

// Round 3
// 564.463 us; speedup vs baseline: 1.3981x; 1.3981x over previous
//
#include <hip/hip_runtime.h>
#include <cstdint>
#include <cstddef>

// ============================================================================
// ResMLP fused kernel for MI355X (gfx950) — round 3
//
//  - Prep: all weights -> one uniform bf16 chunk-major stream in d_ws:
//      ws[190][160][32]  (chunk c, n-row, k)   c<25: embed  25..184: layers
//      185..189: head (n rows 10..159 zero-padded)
//  - Main: 1024 blocks x 256 threads, 64 rows/block through the whole net.
//    4 waves = 2(M) x 2(N), wave tile 32x80. Residual fp32 in registers.
//    B fragments loaded DIRECTLY global->VGPR (coalesced 1KB/instr),
//    2-chunk-deep register pipeline -> NO per-chunk barrier, no W LDS.
//    A fragments from LDS Hs (21.5 KB), prefetched 1 chunk ahead.
//    Barriers only around H writeback (2 per 160-k panel).
// ============================================================================

typedef __attribute__((ext_vector_type(8))) short bfrag8;   // 8 x bf16
typedef __attribute__((ext_vector_type(4))) float facc4;    // 4 x f32

#define MFMA16(a, b, c) __builtin_amdgcn_mfma_f32_16x16x32_bf16((a), (b), (c), 0, 0, 0)

static __device__ __forceinline__ uint16_t f2bf16u(float v) {
    uint32_t u = __builtin_bit_cast(uint32_t, v);
    uint32_t r = u + 0x7FFFu + ((u >> 16) & 1u);
    return (uint16_t)(r >> 16);
}
static __device__ __forceinline__ uint32_t pack2_bf16(float lo, float hi) {
    return (uint32_t)f2bf16u(lo) | ((uint32_t)f2bf16u(hi) << 16);
}

// ---------------------------------------------------------------------------
// Prep: transpose + cast weights into the uniform chunk-major stream.
// Grid = 926 blocks x 256 threads.
//   blocks [0,800):   layer_w [l][160k][160n] -> chunks 25+5l+kchunk
//   blocks [800,925): embed_w [784k][160n]    -> chunks 0..24 (k pad to 800)
//   block  925:       head_w  [160k][10n]     -> chunks 185..189 (n pad 160)
// ---------------------------------------------------------------------------
__global__ __launch_bounds__(256) void resmlp_prep(
    const float* __restrict__ embed_w, const float* __restrict__ layer_w,
    const float* __restrict__ head_w, uint16_t* __restrict__ ws)
{
    int b = blockIdx.x;
    if (b == 925) {
        for (int idx = threadIdx.x; idx < 25600; idx += 256) {
            int n = idx / 160, k = idx - n * 160;
            float v = (n < 10) ? head_w[k * 10 + n] : 0.f;
            ws[(size_t)(185 + (k >> 5)) * 5120 + n * 32 + (k & 31)] = f2bf16u(v);
        }
        return;
    }
    __shared__ float tile[32][33];
    const float* src; int R, rt, ct; size_t chunkBase;
    if (b < 800) {
        int l = b / 25, t = b % 25; rt = t / 5; ct = t % 5;
        src = layer_w + (size_t)l * 25600; R = 160;
        chunkBase = (size_t)(25 + l * 5 + rt) * 5120;
    } else {
        int t = b - 800; rt = t / 5; ct = t % 5;   // rt 0..24 (k chunks), ct 0..4 (n tiles)
        src = embed_w; R = 784;
        chunkBase = (size_t)rt * 5120;
    }
    int tx = threadIdx.x & 31, ty = threadIdx.x >> 5;
#pragma unroll
    for (int j = 0; j < 4; ++j) {
        int r = rt * 32 + ty + j * 8, c = ct * 32 + tx;   // r=k, c=n
        tile[ty + j * 8][tx] = (r < R) ? src[(size_t)r * 160 + c] : 0.f;
    }
    __syncthreads();
#pragma unroll
    for (int j = 0; j < 4; ++j) {
        int n = ct * 32 + ty + j * 8;
        ws[chunkBase + n * 32 + tx] = f2bf16u(tile[tx][ty + j * 8]);
    }
}

// ---------------------------------------------------------------------------
// Main kernel helpers
// ---------------------------------------------------------------------------
__device__ __forceinline__ void stage_x_group(const float* __restrict__ x,
                                              uint16_t* Hs, int r0, int tid, int g)
{
    const int row = tid >> 2;          // 0..63
    const int kc  = g * 160;
    const float* xr = x + (size_t)(r0 + row) * 784 + kc;
#pragma unroll
    for (int j = 0; j < 10; ++j) {
        int c4 = (tid & 3) + j * 4;    // float4 index inside the 160-k chunk
        float4 v;
        if (kc + c4 * 4 < 784) v = *(const float4*)(xr + c4 * 4);
        else                   v = make_float4(0.f, 0.f, 0.f, 0.f);
        uint2 u;
        u.x = pack2_bf16(v.x, v.y);
        u.y = pack2_bf16(v.z, v.w);
        *(uint2*)((char*)Hs + row * 336 + c4 * 8) = u;
    }
}

__device__ __forceinline__ void writeback_h(uint16_t* Hs, const facc4 (&resid)[2][5],
                                            int mg, int NB, int q, int ln)
{
#pragma unroll
    for (int mt = 0; mt < 2; ++mt) {
#pragma unroll
        for (int nt = 0; nt < 5; ++nt) {
#pragma unroll
            for (int r = 0; r < 4; ++r) {
                float v = resid[mt][nt][r];
                float nb = __builtin_bit_cast(float,
                    __builtin_amdgcn_mov_dpp(__builtin_bit_cast(int, v), 0xB1, 0xF, 0xF, true));
                uint32_t pk = (ln & 1) ? pack2_bf16(nb, v) : pack2_bf16(v, nb);
                if (((ln ^ r) & 1) == 0) {
                    int row = mg * 32 + mt * 16 + q * 4 + r;
                    int col = NB + nt * 16 + (ln & ~1);
                    *(uint32_t*)((char*)Hs + row * 336 + col * 2) = pk;
                }
            }
        }
    }
}

// ---------------------------------------------------------------------------
__global__ __launch_bounds__(256, 2) void resmlp_main(
    const float* __restrict__ x,
    const float* __restrict__ embed_b,
    const float* __restrict__ head_b,
    const uint16_t* __restrict__ ws,
    float* __restrict__ out)
{
    __shared__ __align__(16) uint16_t Hs[64 * 168];   // 21504 B

    const int tid  = threadIdx.x;
    const int lane = tid & 63;
    const int wave = tid >> 6;
    const int mg = wave >> 1;          // 0..1  row group (32 rows)
    const int ng = wave & 1;           // 0..1  col group (80 cols)
    const int q  = lane >> 4;          // 0..3
    const int ln = lane & 15;          // 0..15
    const int NB = ng * 80;
    const int r0 = blockIdx.x * 64;

    float bias[5];
#pragma unroll
    for (int nt = 0; nt < 5; ++nt) bias[nt] = embed_b[NB + nt * 16 + ln];
    const float hb = (ln < 10) ? head_b[ln] : 0.f;

    facc4 acc[2][5];
    facc4 resid[2][5];
    bfrag8 B0[5], B1[5];
    bfrag8 A[2][2];
#pragma unroll
    for (int mt = 0; mt < 2; ++mt)
#pragma unroll
        for (int nt = 0; nt < 5; ++nt) acc[mt][nt] = (facc4){0.f, 0.f, 0.f, 0.f};

    // per-wave-lane base into the W stream: row (NB+nt*16+ln), bytes q*16
    const uint16_t* wlane = ws + (NB + ln) * 32 + q * 8;

    // ---- prologue: stage x group 0; preload B chunks 0,1 ----
    stage_x_group(x, Hs, r0, tid, 0);
#pragma unroll
    for (int nt = 0; nt < 5; ++nt) {
        B0[nt] = *(const bfrag8*)(wlane + 0 * 5120 + nt * 512);
        B1[nt] = *(const bfrag8*)(wlane + 1 * 5120 + nt * 512);
    }
    __syncthreads();

    const int abase = (mg * 32 + ln) * 168 + q * 8;   // elem offset in Hs
    const uint16_t* wp = wlane + 2 * 5120;            // next B load target (chunk 2)

    for (int p = 0; p < 19; ++p) {
#pragma unroll
        for (int jj = 0; jj < 10; ++jj) {
            const int akk = jj % 5;                   // compile-time

            // fresh A read at panel start (Hs just (re)written under barriers)
            if (jj == 0 || jj == 5) {
#pragma unroll
                for (int mt = 0; mt < 2; ++mt)
                    A[jj & 1][mt] = *(const bfrag8*)(Hs + abase + mt * (16 * 168) + akk * 32);
            }

            // prefetch next chunk's A frags (same panel only)
            if (jj != 4 && jj != 9) {
#pragma unroll
                for (int mt = 0; mt < 2; ++mt)
                    A[(jj + 1) & 1][mt] =
                        *(const bfrag8*)(Hs + abase + mt * (16 * 168) + ((akk + 1) % 5) * 32);
            }

            // MFMA on chunk c = p*10+jj using B set (jj&1)
            {
                bfrag8* Bc = (jj & 1) ? B1 : B0;
#pragma unroll
                for (int nt = 0; nt < 5; ++nt) {
                    acc[0][nt] = MFMA16(A[jj & 1][0], Bc[nt], acc[0][nt]);
                    acc[1][nt] = MFMA16(A[jj & 1][1], Bc[nt], acc[1][nt]);
                }
            }

            // issue B loads for chunk c+2 into the set just consumed
            if (jj < 8 || p < 18) {
                bfrag8* Bc = (jj & 1) ? B1 : B0;
#pragma unroll
                for (int nt = 0; nt < 5; ++nt)
                    Bc[nt] = *(const bfrag8*)(wp + nt * 512);
                wp += 5120;
            }

            // ---- panel boundary (every 5 chunks) ----
            if (jj == 4 || jj == 9) {
                const int qp = p * 2 + (jj == 9);     // panel index 0..37
                __syncthreads();                      // all A reads of panel done
                if (qp < 4) {
                    stage_x_group(x, Hs, r0, tid, qp + 1);
                } else if (qp == 4) {
                    // end of embed: resid = acc + bias
#pragma unroll
                    for (int mt = 0; mt < 2; ++mt)
#pragma unroll
                        for (int nt = 0; nt < 5; ++nt) {
#pragma unroll
                            for (int r = 0; r < 4; ++r)
                                resid[mt][nt][r] = acc[mt][nt][r] + bias[nt];
                            acc[mt][nt] = (facc4){0.f, 0.f, 0.f, 0.f};
                        }
                    writeback_h(Hs, resid, mg, NB, q, ln);
                } else if (qp < 37) {
                    // end of residual layer: resid += relu(acc)
#pragma unroll
                    for (int mt = 0; mt < 2; ++mt)
#pragma unroll
                        for (int nt = 0; nt < 5; ++nt) {
#pragma unroll
                            for (int r = 0; r < 4; ++r)
                                resid[mt][nt][r] += fmaxf(acc[mt][nt][r], 0.f);
                            acc[mt][nt] = (facc4){0.f, 0.f, 0.f, 0.f};
                        }
                    writeback_h(Hs, resid, mg, NB, q, ln);
                } else {
                    // qp == 37: head epilogue + store
                    if (ng == 0) {
#pragma unroll
                        for (int mt = 0; mt < 2; ++mt)
#pragma unroll
                            for (int r = 0; r < 4; ++r) {
                                int row = r0 + mg * 32 + mt * 16 + q * 4 + r;
                                if (ln < 10) out[row * 10 + ln] = acc[mt][0][r] + hb;
                            }
                    }
                }
                if (qp < 37) __syncthreads();         // Hs writes visible
            }
        }
    }
}

// ---------------------------------------------------------------------------
extern "C" void kernel_launch(void* const* d_in, const int* in_sizes, int n_in,
                              void* d_out, int out_size, void* d_ws, size_t ws_size,
                              hipStream_t stream) {
    (void)in_sizes; (void)n_in; (void)out_size; (void)ws_size;
    const float* x       = (const float*)d_in[0];
    const float* embed_w = (const float*)d_in[1];
    const float* embed_b = (const float*)d_in[2];
    const float* layer_w = (const float*)d_in[3];
    const float* head_w  = (const float*)d_in[4];
    const float* head_b  = (const float*)d_in[5];
    float* out = (float*)d_out;

    uint16_t* ws = (uint16_t*)d_ws;   // 190*5120 elems = 1.95 MB

    resmlp_prep<<<926, 256, 0, stream>>>(embed_w, layer_w, head_w, ws);
    resmlp_main<<<1024, 256, 0, stream>>>(x, embed_b, head_b, ws, out);
}